// Round 19
// baseline (817.847 us; speedup 1.0000x reference)
//
#include <hip/hip_runtime.h>
#include <cstdint>
#include <cstring>

typedef unsigned short u16;
typedef __attribute__((ext_vector_type(8))) short short8;     // 8 bf16 for MFMA A/B
typedef __attribute__((ext_vector_type(8))) unsigned short ushortx8;
typedef __attribute__((ext_vector_type(4))) float floatx4;    // MFMA C/D

#define DEV __device__ __forceinline__

DEV u16 f2bf(float f) {
  union { float f; uint32_t u; } x; x.f = f;
  uint32_t r = x.u + 0x7fffu + ((x.u >> 16) & 1u);   // RNE
  return (u16)(r >> 16);
}
DEV float bf2f(u16 h) {
  union { float f; uint32_t u; } x; x.u = ((uint32_t)h) << 16;
  return x.f;
}
DEV u16 f2h(float f) {                                 // f32 -> f16 bits (v_cvt, RNE)
  union { u16 u; _Float16 h; } x; x.h = (_Float16)f; return x.u;
}
DEV float h2f(u16 h) {
  union { u16 u; _Float16 h; } x; x.u = h; return (float)x.h;
}
DEV float fexp2(float x) { return __builtin_amdgcn_exp2f(x); }  // v_exp_f32 (base-2)
// tanh-formulation gelu, branchless, hw v_exp_f32. |err| vs exact erf-gelu < 1e-3.
DEV float fast_gelu(float g) {
  float u = 0.7978845608f * (g + 0.044715f * g * g * g);
  float e = fexp2(-2.885390082f * fabsf(u));          // exp(-2u) = exp2(-2*log2e*u)
  float th = (1.0f - e) / (1.0f + e);
  th = (u < 0.0f) ? -th : th;
  return 0.5f * g * (1.0f + th);
}
// async global->LDS, 16B per lane. LDS dest = wave-uniform base + lane*16.
DEV void gload_lds16(const void* g, void* lds) {
  __builtin_amdgcn_global_load_lds(
      (const __attribute__((address_space(1))) char*)(uintptr_t)g,
      (__attribute__((address_space(3))) char*)(uintptr_t)lds, 16, 0, 0);
}

// ---------------- fused prep: cvt + 3 transposes + w1p + rope tables ----------------
// [0,4096) x->bf16 ; [4096,12288) wqkv/wo/w2 transpose ; [12288,20480) w1p ;
// [20480,20992) rope tables. Block-uniform branches.
__global__ __launch_bounds__(256) void k_prep(const float* __restrict__ x,
                                              u16* __restrict__ xb,
                                              const float* __restrict__ Wq,
                                              u16* __restrict__ WqT,
                                              const float* __restrict__ Wo,
                                              u16* __restrict__ WoT,
                                              const float* __restrict__ W2,
                                              u16* __restrict__ W2T,
                                              const float* __restrict__ W1,
                                              u16* __restrict__ W1Tp,
                                              float* __restrict__ ct,
                                              float* __restrict__ st) {
  __shared__ u16 t[64][70];
  const int id = blockIdx.x;
  if (id < 4096) {
    int i = (id * 256 + (int)threadIdx.x) * 8;
    float4 a = *(const float4*)(x + i);
    float4 b = *(const float4*)(x + i + 4);
    ushortx8 o;
    o[0] = f2bf(a.x); o[1] = f2bf(a.y); o[2] = f2bf(a.z); o[3] = f2bf(a.w);
    o[4] = f2bf(b.x); o[5] = f2bf(b.y); o[6] = f2bf(b.z); o[7] = f2bf(b.w);
    *(ushortx8*)(xb + i) = o;
  } else if (id < 20480) {
    const float* W; u16* Wt; int R, C, c0, r0;
    int src;                                     // source column (with w1 permute)
    int cx = threadIdx.x & 15, ry = threadIdx.x >> 4;
    if (id < 12288) {
      int tix;
      int i2 = id - 4096;
      if (i2 < 3072)      { W = Wq; Wt = WqT; R = 2048; C = 6144; tix = i2; }
      else if (i2 < 4096) { W = Wo; Wt = WoT; R = 2048; C = 2048; tix = i2 - 3072; }
      else                { W = W2; Wt = W2T; R = 8192; C = 2048; tix = i2 - 4096; }
      int ntc = C >> 6;
      c0 = (tix % ntc) * 64; r0 = (tix / ntc) * 64;
      src = c0 + cx * 4;
    } else {
      int iw = id - 12288;                       // 256 x 32 grid flattened
      W = W1; Wt = W1Tp; R = 2048; C = 16384;
      c0 = (iw & 255) * 64; r0 = (iw >> 8) * 64;
      int eta = c0 + cx * 4;
      int Bq = eta >> 8, ii = eta & 255, wn = (ii >> 6) & 3, rr = ii & 63,
          n = rr >> 4, tt = rr & 15;
      src = Bq * 128 + wn * 32 + (n & 1) * 16 + tt + ((n >= 2) ? 8192 : 0);
    }
#pragma unroll
    for (int i = 0; i < 4; ++i) {
      int row = ry + i * 16;
      float4 v = *(const float4*)(W + (size_t)(r0 + row) * C + src);
      ushort2 lo, hi;
      lo.x = f2bf(v.x); lo.y = f2bf(v.y);
      hi.x = f2bf(v.z); hi.y = f2bf(v.w);
      *(ushort2*)&t[row][cx * 4] = lo;
      *(ushort2*)&t[row][cx * 4 + 2] = hi;
    }
    __syncthreads();
#pragma unroll
    for (int i = 0; i < 4; ++i) {
      int col = ry + i * 16;
      ushort4 o;
      o.x = t[cx * 4 + 0][col]; o.y = t[cx * 4 + 1][col];
      o.z = t[cx * 4 + 2][col]; o.w = t[cx * 4 + 3][col];
      *(ushort4*)(Wt + (size_t)(c0 + col) * R + r0 + cx * 4) = o;
    }
  } else {
    int i = (id - 20480) * 256 + (int)threadIdx.x;  // < 2048*64
    int s = i >> 6, j = i & 63;
    float invf = 1.0f / powf(10000.0f, (float)j * (1.0f / 64.0f));
    float ang = (float)s * invf;
    ct[i] = cosf(ang);
    st[i] = sinf(ang);
  }
}

// ---------------- G1 GEMM 128x256 (8-wave, BK=32, quad-buffer, 768 blocks) -------
// qkv = x @ wqkvT^T + b; fused rope->qr/kr (q prescaled), v->vt transpose.
__global__ __launch_bounds__(512, 1) void k_gemm128(const u16* __restrict__ A,
                                                    const u16* __restrict__ Bt,
                                                    const float* __restrict__ bias,
                                                    u16* __restrict__ qrO,
                                                    u16* __restrict__ krO,
                                                    u16* __restrict__ vtO,
                                                    const float* __restrict__ ctabO,
                                                    const float* __restrict__ stabO) {
  constexpr int K = 2048;
  constexpr int nt = K / 32;                      // 64
  __shared__ __align__(16) u16 lds[4][12288];     // 96KB: per buf A[0,4096) B[4096,12288)
  const int tid = threadIdx.x;
  const int w = tid >> 6, lane = tid & 63;
  const int l15 = lane & 15, l4 = lane >> 4;
  const int wm = w >> 2, wn = w & 3;              // 2 x 4 waves; wave = 64x64 out
  const int xcd = blockIdx.x & 7, loc = blockIdx.x >> 3;
  const int swz = xcd * 96 + loc;
  const int bm = swz / 24, bn = swz % 24;

  const size_t abase = (size_t)bm * 128 * K;
  const size_t bbase = (size_t)bn * 256 * K;

  const int srA = tid >> 2;                       // A row (0..127)
  const int scA = (tid & 3) ^ ((srA >> 1) & 3);   // swizzled granule col
  auto stageA = [&](int kt) {
    gload_lds16(A + abase + (size_t)srA * K + kt * 32 + scA * 8,
                (void*)&lds[kt & 3][(size_t)tid * 8]);
  };
  auto stageB = [&](int kt, int li) {
    int g = li * 512 + tid;
    int row = g >> 2;
    int sc = (g & 3) ^ ((row >> 1) & 3);
    gload_lds16(Bt + bbase + (size_t)row * K + kt * 32 + sc * 8,
                (void*)&lds[kt & 3][4096 + (size_t)g * 8]);
  };
  const int fro = l15 * 32 + (l4 ^ ((l15 >> 1) & 3)) * 8;

  floatx4 acc[4][4];
  floatx4 zero = {0.f, 0.f, 0.f, 0.f};
#pragma unroll
  for (int m = 0; m < 4; ++m)
#pragma unroll
    for (int n = 0; n < 4; ++n) acc[m][n] = zero;

  for (int kt = 0; kt < 3; ++kt) { stageA(kt); stageB(kt, 0); stageB(kt, 1); }

  for (int t = 0; t < nt; ++t) {
    const int buf = t & 3;
    if (t < nt - 2)       asm volatile("s_waitcnt vmcnt(6)" ::: "memory");
    else if (t == nt - 2) asm volatile("s_waitcnt vmcnt(3)" ::: "memory");
    else                  asm volatile("s_waitcnt vmcnt(0)" ::: "memory");
    __builtin_amdgcn_sched_barrier(0);
    __builtin_amdgcn_s_barrier();
    const u16* Ab = &lds[buf][wm * 2048 + fro];
    const u16* Bb = &lds[buf][4096 + wn * 2048 + fro];
    short8 av[4], bv[4];
    // ---- phase 0: B all, A m0-1, 8 MFMA
#pragma unroll
    for (int n = 0; n < 4; ++n) bv[n] = *(const short8*)(Bb + n * 512);
    av[0] = *(const short8*)(Ab);
    av[1] = *(const short8*)(Ab + 512);
    if (t + 3 < nt) { stageA(t + 3); stageB(t + 3, 0); }
    asm volatile("s_waitcnt lgkmcnt(0)" ::: "memory");
    __builtin_amdgcn_sched_barrier(0);
    __builtin_amdgcn_s_setprio(1);
#pragma unroll
    for (int i = 0; i < 2; ++i)
#pragma unroll
      for (int n = 0; n < 4; ++n)
        acc[i][n] = __builtin_amdgcn_mfma_f32_16x16x32_bf16(av[i], bv[n], acc[i][n], 0, 0, 0);
    __builtin_amdgcn_s_setprio(0);
    __builtin_amdgcn_s_barrier();
    // ---- phase 1: A m2-3, 8 MFMA
    av[2] = *(const short8*)(Ab + 2 * 512);
    av[3] = *(const short8*)(Ab + 3 * 512);
    if (t + 3 < nt) stageB(t + 3, 1);
    asm volatile("s_waitcnt lgkmcnt(0)" ::: "memory");
    __builtin_amdgcn_sched_barrier(0);
    __builtin_amdgcn_s_setprio(1);
#pragma unroll
    for (int i = 0; i < 2; ++i)
#pragma unroll
      for (int n = 0; n < 4; ++n)
        acc[2 + i][n] = __builtin_amdgcn_mfma_f32_16x16x32_bf16(av[2 + i], bv[n], acc[2 + i][n], 0, 0, 0);
    __builtin_amdgcn_s_setprio(0);
  }

  // ---- fused epilogue: bounce full 128x256 tile through padded LDS [128][264]
  constexpr int PAD = 264;
  u16* T = (u16*)lds;                             // 128*264*2 = 67.6KB <= 96KB
  __syncthreads();                                // main-loop LDS reads complete
#pragma unroll
  for (int n = 0; n < 4; ++n) {
    float bb = bias[bn * 256 + wn * 64 + n * 16 + l15];
#pragma unroll
    for (int m = 0; m < 4; ++m)
#pragma unroll
      for (int j = 0; j < 4; ++j)
        T[(wm * 64 + m * 16 + l4 * 4 + j) * PAD + wn * 64 + n * 16 + l15] =
            f2bf(acc[m][n][j] + bb);
  }
  __syncthreads();
  const int bq = bm >> 4;                         // batch
  const int srow0 = (bm & 15) * 128;              // tile s base
  if (bn < 16) {
    // rope: task (sl 0..127, hh 0..1, t2 0..1) = tid
    int sl = tid >> 2, hh = (tid >> 1) & 1, t2 = tid & 1;
    const u16* row = T + sl * PAD + hh * 128;
    int s = srow0 + sl;
    int head = 2 * (bn & 7) + hh;
    u16* dst = (bn < 8 ? qrO : krO) +
               (((size_t)bq * 16 + head) * 2048 + s) * 128 + t2 * 64;
    const float* ctr = ctabO + (s << 6);
    const float* str2 = stabO + (s << 6);
    const float qs = (bn < 8) ? 0.12751744f : 1.0f;   // 1/sqrt(128)*log2(e) for q
#pragma unroll
    for (int ch = 0; ch < 8; ++ch) {
      int d0 = t2 * 64 + ch * 8;
      ushortx8 xv = *(const ushortx8*)(row + d0);
      float xp = bf2f(row[(d0 + 126) & 127]);     // x[d0-2] (wrap -> x[126])
      int f0 = d0 & 63;
      float4 c0v = *(const float4*)(ctr + f0);
      float4 c1v = *(const float4*)(ctr + f0 + 4);
      float4 s0v = *(const float4*)(str2 + f0);
      float4 s1v = *(const float4*)(str2 + f0 + 4);
      float cc[8] = {c0v.x, c0v.y, c0v.z, c0v.w, c1v.x, c1v.y, c1v.z, c1v.w};
      float sn[8] = {s0v.x, s0v.y, s0v.z, s0v.w, s1v.x, s1v.y, s1v.z, s1v.w};
      ushortx8 o;
#pragma unroll
      for (int pr = 0; pr < 4; ++pr) {
        float xe = bf2f((u16)xv[2 * pr]), xo = bf2f((u16)xv[2 * pr + 1]);
        o[2 * pr]     = f2bf((-xo * cc[2 * pr] + xp * sn[2 * pr]) * qs);
        o[2 * pr + 1] = f2bf(( xe * cc[2 * pr + 1] - xo * sn[2 * pr + 1]) * qs);
        xp = xe;
      }
      *(ushortx8*)(dst + ch * 8) = o;
    }
  } else {
    // v: in-reg 8x8 transpose -> vt[bq][head*128+d][s]
    int hh = tid >> 8, dg = (tid >> 4) & 15, sc2 = tid & 15;
    int head = 2 * (bn - 16) + hh;
    int s0 = srow0 + sc2 * 8;
    ushortx8 r[8];
#pragma unroll
    for (int i = 0; i < 8; ++i)
      r[i] = *(const ushortx8*)(T + (sc2 * 8 + i) * PAD + hh * 128 + dg * 8);
    u16* vbase = vtO + ((size_t)bq * 2048 + head * 128 + dg * 8) * 2048 + s0;
#pragma unroll
    for (int j2 = 0; j2 < 8; ++j2) {
      ushortx8 o;
#pragma unroll
      for (int i = 0; i < 8; ++i) o[i] = r[i][j2];
      *(ushortx8*)(vbase + (size_t)j2 * 2048) = o;
    }
  }
}

// ---------------- GEMM 256x256 deep-pipelined (8-wave, BK=32, quad-buffer) --------
// C[M][N] = A[M][K] @ Bt[N][K]^T, optional split-K (nsplit partials stacked in C).
// EPI 0: bf16 out = acc + bias. EPI 2: f16 raw partial (split-K).
// EPI 3: fused MLP front. Tile body: EXACT r3 structure.
template <int EPI>
__global__ __launch_bounds__(512, 2) void k_gemm256(const u16* __restrict__ A,
                                                    const u16* __restrict__ Bt,
                                                    void* __restrict__ C,
                                                    const float* __restrict__ bias,
                                                    int M, int N, int K, int nsplit) {
  __shared__ __align__(16) u16 lds[4][2][8192];   // 128 KiB: [buf][A/B][256*32]
  const int tid = threadIdx.x;
  const int w = tid >> 6, lane = tid & 63;
  const int l15 = lane & 15, l4 = lane >> 4;
  const int wm = w >> 2, wn = w & 3;              // wave grid 2 x 4
  const int nbn = N >> 8;
  const int nbm = M >> 8;

  int bm, bn, split = 0;
  if (nsplit == 1 && nbm == 16 && (nbn & 7) == 0) {
    const int xcd = blockIdx.x & 7, l = blockIdx.x >> 3;
    const int xr = xcd >> 1, xc = xcd & 1;
    const int stn = l >> 4, lbm = (l >> 2) & 3, lbn = l & 3;
    bm = xr * 4 + lbm;
    bn = xc * (nbn >> 1) + stn * 4 + lbn;
  } else {
    const int nwg = gridDim.x;
    const int q = nwg >> 3, r8 = nwg & 7;
    const int xcd = blockIdx.x & 7, loc = blockIdx.x >> 3;
    const int swz = (xcd < r8 ? xcd * (q + 1) : r8 * (q + 1) + (xcd - r8) * q) + loc;
    const int ntiles = nwg / nsplit;
    split = swz / ntiles;
    const int tix = swz % ntiles;
    bm = tix / nbn; bn = tix % nbn;
  }
  const int klen = K / nsplit;
  const int kofs = split * klen;

  const size_t abase = (size_t)bm * 256 * K + kofs;
  const size_t bbase = (size_t)bn * 256 * K + kofs;
  const int nt = klen >> 5;

  const int sr = tid >> 2;                        // row within half (0..127)
  const int sc = (tid & 3) ^ ((sr >> 1) & 3);     // swizzled granule col
  auto stage = [&](int kt, int li, int op) {
    const u16* src = op ? (Bt + bbase) : (A + abase);
    gload_lds16(src + (size_t)(li * 128 + sr) * K + kt * 32 + sc * 8,
                (void*)&lds[kt & 3][op][(li * 512 + w * 64) * 8]);
  };

  const int fro = l15 * 32 + (l4 ^ ((l15 >> 1) & 3)) * 8;

  floatx4 acc[8][4];
  floatx4 zero = {0.f, 0.f, 0.f, 0.f};
#pragma unroll
  for (int m = 0; m < 8; ++m)
#pragma unroll
    for (int n = 0; n < 4; ++n) acc[m][n] = zero;

  for (int kt = 0; kt < 3; ++kt)
    if (kt < nt) {
      stage(kt, 0, 0); stage(kt, 0, 1);
      stage(kt, 1, 0); stage(kt, 1, 1);
    }

  for (int t = 0; t < nt; ++t) {
    const int buf = t & 3;
    if (t < nt - 2)       asm volatile("s_waitcnt vmcnt(8)" ::: "memory");
    else if (t == nt - 2) asm volatile("s_waitcnt vmcnt(4)" ::: "memory");
    else                  asm volatile("s_waitcnt vmcnt(0)" ::: "memory");
    __builtin_amdgcn_sched_barrier(0);
    __builtin_amdgcn_s_barrier();            // all waves' tile-t loads landed
    const u16* Ab = &lds[buf][0][wm * 4096 + fro];
    const u16* Bb = &lds[buf][1][wn * 2048 + fro];
    short8 av[4], bv[4];
    // ---- phase 0: B all, A m0-3, 16 MFMA
#pragma unroll
    for (int n = 0; n < 4; ++n) bv[n] = *(const short8*)(Bb + n * 512);
#pragma unroll
    for (int i = 0; i < 4; ++i) av[i] = *(const short8*)(Ab + i * 512);
    if (t + 3 < nt) { stage(t + 3, 0, 0); stage(t + 3, 0, 1); }
    asm volatile("s_waitcnt lgkmcnt(0)" ::: "memory");
    __builtin_amdgcn_sched_barrier(0);
    __builtin_amdgcn_s_setprio(1);
#pragma unroll
    for (int i = 0; i < 4; ++i)
#pragma unroll
      for (int n = 0; n < 4; ++n)
        acc[i][n] = __builtin_amdgcn_mfma_f32_16x16x32_bf16(av[i], bv[n], acc[i][n], 0, 0, 0);
    __builtin_amdgcn_s_setprio(0);
    __builtin_amdgcn_s_barrier();
    // ---- phase 1: A m4-7, 16 MFMA (bv reused from regs)
#pragma unroll
    for (int i = 0; i < 4; ++i) av[i] = *(const short8*)(Ab + (4 + i) * 512);
    if (t + 3 < nt) { stage(t + 3, 1, 0); stage(t + 3, 1, 1); }
    asm volatile("s_waitcnt lgkmcnt(0)" ::: "memory");
    __builtin_amdgcn_sched_barrier(0);
    __builtin_amdgcn_s_setprio(1);
#pragma unroll
    for (int i = 0; i < 4; ++i)
#pragma unroll
      for (int n = 0; n < 4; ++n)
        acc[4 + i][n] = __builtin_amdgcn_mfma_f32_16x16x32_bf16(av[i], bv[n], acc[4 + i][n], 0, 0, 0);
    __builtin_amdgcn_s_setprio(0);
  }

  const int row0 = bm * 256 + wm * 128, col0 = bn * 256 + wn * 64;
  if (EPI == 2) {
    // f16 partials: |p| ~ O(1), f16 rel err 4.9e-4 -> negligible; halves traffic
    u16* P = (u16*)C + (size_t)split * M * N;
#pragma unroll
    for (int n = 0; n < 4; ++n) {
      int col = col0 + n * 16 + l15;
#pragma unroll
      for (int m = 0; m < 8; ++m)
#pragma unroll
        for (int j = 0; j < 4; ++j) {
          int row = row0 + m * 16 + l4 * 4 + j;
          P[(size_t)row * N + col] = f2h(acc[m][n][j]);
        }
    }
  } else if (EPI == 3) {
    // fused bias + act = a*gelu(g); pairing in-register via w1 permutation.
    __syncthreads();                              // main-loop LDS reads complete
    u16* ep = ((u16*)lds) + w * 4096;             // [128][32] u16 per wave
    const int colA = bn * 128 + wn * 32;          // act col base for this wave
#pragma unroll
    for (int n = 0; n < 2; ++n) {
      float ba = bias[colA + n * 16 + l15];
      float bg = bias[8192 + colA + n * 16 + l15];
#pragma unroll
      for (int m = 0; m < 8; ++m)
#pragma unroll
        for (int j = 0; j < 4; ++j) {
          float a = acc[m][n][j] + ba;
          float g = acc[m][n + 2][j] + bg;
          ep[(m * 16 + l4 * 4 + j) * 32 + n * 16 + l15] = f2bf(a * fast_gelu(g));
        }
    }
    const int rr = lane >> 2, cg = lane & 3;
    u16* Cg = (u16*)C;
    const int Nact = N >> 1;
#pragma unroll
    for (int pass = 0; pass < 8; ++pass) {
      short8 v = *(const short8*)&ep[(pass * 16 + rr) * 32 + cg * 8];
      size_t grow = row0 + pass * 16 + rr;
      *(short8*)&Cg[grow * Nact + colA + cg * 8] = v;
    }
  } else {
    // EPI 0: coalesced bf16 epilogue: per-wave 16KB LDS region, 128B row stores
    __syncthreads();                              // main-loop LDS reads complete
    u16* ep = ((u16*)lds) + w * 8192;             // [128][64] u16 per wave
#pragma unroll
    for (int n = 0; n < 4; ++n) {
      float bb = bias[col0 + n * 16 + l15];
#pragma unroll
      for (int m = 0; m < 8; ++m)
#pragma unroll
        for (int j = 0; j < 4; ++j)
          ep[(m * 16 + l4 * 4 + j) * 64 + n * 16 + l15] = f2bf(acc[m][n][j] + bb);
    }
    const int rr = lane >> 3, cg = lane & 7;
    u16* Cg = (u16*)C;
#pragma unroll
    for (int pass = 0; pass < 16; ++pass) {
      short8 v = *(const short8*)&ep[(pass * 8 + rr) * 64 + cg * 8];
      size_t grow = row0 + pass * 8 + rr;
      *(short8*)&Cg[grow * N + col0 + cg * 8] = v;
    }
  }
}

// ---------------- flash attention (QBLK=256, 8 waves, 256 blocks) ----------------
// Qr,Kr [B,H,S,HD] bf16 (q prescaled by scale*log2e) ; Vt [B,H,HD,S] ; O bf16
// r19: QBLK 128->256 (each wave owns TWO 16-row groups, processed sequentially
// per k-tile) -> 256 blocks = 1/CU; halves total K/V staging traffic + staging
// rounds at identical MFMA/softmax work. All state statically indexed via
// unrolled g loops (rule 20); branch-free updates (r8 lesson).
__global__ __launch_bounds__(512, 1) void k_attn(const u16* __restrict__ Qr,
                                                 const u16* __restrict__ Kr,
                                                 const u16* __restrict__ Vt,
                                                 const int* __restrict__ mask,
                                                 u16* __restrict__ O) {
  constexpr int S = 2048, HD = 128, H = 16;
  __shared__ __align__(16) u16 Ksh[64 * 128];      // [key][hd], swizzled (16KB)
  __shared__ __align__(16) u16 Vsh[128 * 64];      // [hd][key], swizzled (16KB)
  __shared__ __align__(16) u16 Psh[8][2][16 * 72]; // per-wave/group P (36.9KB)
  __shared__ float Msh[2048];                      // mask add (8KB)

  const int bid = blockIdx.x;                   // 256 blocks
  const int xcd = bid & 7, local = bid >> 3;    // 32 blocks per XCD
  const int bh = xcd * 4 + (local >> 3);        // 4 heads per XCD
  const int qt = local & 7;                     // 8 q-tiles of 256 rows
  const int b = bh >> 4, h = bh & 15;
  const int tid = threadIdx.x, wave = tid >> 6, lane = tid & 63;
  const int l15 = lane & 15, l4 = lane >> 4;
  const size_t bhs = (size_t)(b * H + h);
  const u16* Qb = Qr + bhs * S * HD;
  const u16* Kb = Kr + bhs * S * HD;
  const u16* Vb = Vt + bhs * HD * S;

  for (int i = tid; i < 2048; i += 512)
    Msh[i] = (mask[b * S + i] == 1) ? 0.0f : -1e30f;

  short8 qf[2][4];
#pragma unroll
  for (int g = 0; g < 2; ++g) {
    int qrow = qt * 256 + g * 128 + wave * 16 + l15;
#pragma unroll
    for (int kk = 0; kk < 4; ++kk)
      qf[g][kk] = *(const short8*)&Qb[(size_t)qrow * HD + kk * 32 + l4 * 8];
  }

  // staging geometry (each thread: 2 K granules + 2 V granules per tile)
  const int giA = tid, giB = 512 + tid;
  const int rKA = giA >> 4, gKA = giA & 15;
  const int rKB = giB >> 4, gKB = giB & 15;
  const int gsKA = (gKA & 8) | ((gKA ^ rKA) & 7);
  const int gsKB = (gKB & 8) | ((gKB ^ rKB) & 7);
  const int rVA = giA >> 3, gVA = giA & 7;
  const int rVB = giB >> 3, gVB = giB & 7;
  const int gsVA = (gVA ^ rVA) & 7;
  const int gsVB = (gVB ^ rVB) & 7;
  const u16* pKA = Kb + (size_t)rKA * HD + gsKA * 8;   // + ktile*8192
  const u16* pKB = Kb + (size_t)rKB * HD + gsKB * 8;
  const u16* pVA = Vb + (size_t)rVA * S + gsVA * 8;    // + ktile*64
  const u16* pVB = Vb + (size_t)rVB * S + gsVB * 8;

  float m_run[2][4], l_run[2][4];   // per-group, per-row; l per-lane partial
  floatx4 o_acc[2][8];
  floatx4 zero = {0.f, 0.f, 0.f, 0.f};
#pragma unroll
  for (int g = 0; g < 2; ++g) {
#pragma unroll
    for (int j = 0; j < 4; ++j) { m_run[g][j] = -1e30f; l_run[g][j] = 0.f; }
#pragma unroll
    for (int n = 0; n < 8; ++n) o_acc[g][n] = zero;
  }

  // prologue: load tile 0 into regs
  uint4 k0 = *(const uint4*)pKA;
  uint4 k1 = *(const uint4*)pKB;
  uint4 v0 = *(const uint4*)pVA;
  uint4 v1 = *(const uint4*)pVB;

  for (int ktile = 0; ktile < S / 64; ++ktile) {
    __builtin_amdgcn_sched_barrier(0);
    __builtin_amdgcn_s_barrier();       // all waves finished reading prev tile
    __builtin_amdgcn_sched_barrier(0);
    *(uint4*)&Ksh[(size_t)(0 * 512 + tid) * 8] = k0;
    *(uint4*)&Ksh[(size_t)(1 * 512 + tid) * 8] = k1;
    *(uint4*)&Vsh[(size_t)(0 * 512 + tid) * 8] = v0;
    *(uint4*)&Vsh[(size_t)(1 * 512 + tid) * 8] = v1;
    if (ktile + 1 < S / 64) {           // issue next tile's loads (stay in flight)
      k0 = *(const uint4*)(pKA + (size_t)(ktile + 1) * 8192);
      k1 = *(const uint4*)(pKB + (size_t)(ktile + 1) * 8192);
      v0 = *(const uint4*)(pVA + (size_t)(ktile + 1) * 64);
      v1 = *(const uint4*)(pVB + (size_t)(ktile + 1) * 64);
    }
    asm volatile("s_waitcnt lgkmcnt(0)" ::: "memory");  // own ds_writes done
    __builtin_amdgcn_sched_barrier(0);
    __builtin_amdgcn_s_barrier();       // all waves' writes visible
    __builtin_amdgcn_sched_barrier(0);

#pragma unroll
    for (int g = 0; g < 2; ++g) {
      floatx4 s_acc[4];
#pragma unroll
      for (int nf = 0; nf < 4; ++nf) s_acc[nf] = zero;
      __builtin_amdgcn_s_setprio(1);
#pragma unroll
      for (int kk = 0; kk < 4; ++kk) {
#pragma unroll
        for (int nf = 0; nf < 4; ++nf) {
          int key = nf * 16 + l15;
          int G = kk * 4 + l4;
          int lg = (G & 8) | ((G ^ key) & 7);
          short8 kv = *(const short8*)&Ksh[key * 128 + lg * 8];
          s_acc[nf] = __builtin_amdgcn_mfma_f32_16x16x32_bf16(qf[g][kk], kv, s_acc[nf], 0, 0, 0);
        }
      }
      __builtin_amdgcn_s_setprio(0);

      float p[4][4];
#pragma unroll
      for (int nf = 0; nf < 4; ++nf) {
        float ma = Msh[ktile * 64 + nf * 16 + l15];
#pragma unroll
        for (int j = 0; j < 4; ++j) p[nf][j] = s_acc[nf][j] + ma;   // exp2 units
      }
#pragma unroll
      for (int j = 0; j < 4; ++j) {
        float mx = fmaxf(fmaxf(p[0][j], p[1][j]), fmaxf(p[2][j], p[3][j]));
        mx = fmaxf(mx, __shfl_xor(mx, 1));
        mx = fmaxf(mx, __shfl_xor(mx, 2));
        mx = fmaxf(mx, __shfl_xor(mx, 4));
        mx = fmaxf(mx, __shfl_xor(mx, 8));
        float mnew = fmaxf(m_run[g][j], mx);
        float corr = fexp2(m_run[g][j] - mnew);
        float ps = 0.f;
#pragma unroll
        for (int nf = 0; nf < 4; ++nf) {
          p[nf][j] = fexp2(p[nf][j] - mnew);
          ps += p[nf][j];
        }
        l_run[g][j] = l_run[g][j] * corr + ps;
        m_run[g][j] = mnew;
#pragma unroll
        for (int n = 0; n < 8; ++n) o_acc[g][n][j] *= corr;
      }

#pragma unroll
      for (int nf = 0; nf < 4; ++nf)
#pragma unroll
        for (int j = 0; j < 4; ++j)
          Psh[wave][g][(l4 * 4 + j) * 72 + nf * 16 + l15] = f2bf(p[nf][j]);

      __builtin_amdgcn_s_setprio(1);
#pragma unroll
      for (int ks = 0; ks < 2; ++ks) {
        short8 pa = *(const short8*)&Psh[wave][g][l15 * 72 + ks * 32 + l4 * 8];
#pragma unroll
        for (int nf2 = 0; nf2 < 8; ++nf2) {
          int hd = nf2 * 16 + l15;
          int G = ks * 4 + l4;
          short8 vv = *(const short8*)&Vsh[hd * 64 + ((G ^ hd) & 7) * 8];
          o_acc[g][nf2] = __builtin_amdgcn_mfma_f32_16x16x32_bf16(pa, vv, o_acc[g][nf2], 0, 0, 0);
        }
      }
      __builtin_amdgcn_s_setprio(0);
    }
  }

#pragma unroll
  for (int g = 0; g < 2; ++g) {
#pragma unroll
    for (int j = 0; j < 4; ++j) {
      float ls = l_run[g][j];
      ls += __shfl_xor(ls, 1); ls += __shfl_xor(ls, 2);
      ls += __shfl_xor(ls, 4); ls += __shfl_xor(ls, 8);
      l_run[g][j] = ls;
    }
#pragma unroll
    for (int j = 0; j < 4; ++j) {
      float inv = 1.0f / l_run[g][j];
      int srow = qt * 256 + g * 128 + wave * 16 + l4 * 4 + j;
      size_t orow = ((size_t)b * S + srow) * 2048 + h * 128;
#pragma unroll
      for (int nf2 = 0; nf2 < 8; ++nf2)
        O[orow + nf2 * 16 + l15] = f2bf(o_acc[g][nf2][j] * inv);
    }
  }
}

// ---------------- fused split-K combine + rmsnorm over D=2048 ----------------
// rms_fuse1: v = p0+p1(f16)+bias+resid(f32); x1 = rmsnorm -> bf16 only
__global__ __launch_bounds__(256) void k_rms_fuse1(const u16* __restrict__ p0,
                                                   const u16* __restrict__ p1,
                                                   const float* __restrict__ bias,
                                                   const float* __restrict__ resid,
                                                   const float* __restrict__ w,
                                                   u16* __restrict__ ob) {
  int row = blockIdx.x;
  int t = threadIdx.x;
  size_t base = (size_t)row * 2048 + t * 8;
  ushortx8 a = *(const ushortx8*)(p0 + base);
  ushortx8 b = *(const ushortx8*)(p1 + base);
  float4 r0 = *(const float4*)(resid + base);
  float4 r1 = *(const float4*)(resid + base + 4);
  float4 c0 = *(const float4*)(bias + t * 8);
  float4 c1 = *(const float4*)(bias + t * 8 + 4);
  float rr[8] = {r0.x, r0.y, r0.z, r0.w, r1.x, r1.y, r1.z, r1.w};
  float cc[8] = {c0.x, c0.y, c0.z, c0.w, c1.x, c1.y, c1.z, c1.w};
  float v[8];
#pragma unroll
  for (int e = 0; e < 8; ++e)
    v[e] = h2f((u16)a[e]) + h2f((u16)b[e]) + rr[e] + cc[e];
  float ss = 0.f;
#pragma unroll
  for (int e = 0; e < 8; ++e) ss += v[e] * v[e];
#pragma unroll
  for (int d = 1; d < 64; d <<= 1) ss += __shfl_xor(ss, d);
  __shared__ float sred[4];
  if ((t & 63) == 0) sred[t >> 6] = ss;
  __syncthreads();
  float tot = sred[0] + sred[1] + sred[2] + sred[3];
  float scale = rsqrtf(tot * (1.0f / 2048.0f) + 1e-6f);
  const float* wp = w + t * 8;
  ushort4 q0, q1;
  q0.x = f2bf(v[0] * wp[0] * scale); q0.y = f2bf(v[1] * wp[1] * scale);
  q0.z = f2bf(v[2] * wp[2] * scale); q0.w = f2bf(v[3] * wp[3] * scale);
  q1.x = f2bf(v[4] * wp[4] * scale); q1.y = f2bf(v[5] * wp[5] * scale);
  q1.z = f2bf(v[6] * wp[6] * scale); q1.w = f2bf(v[7] * wp[7] * scale);
  *(ushort4*)(ob + base) = q0;
  *(ushort4*)(ob + base + 4) = q1;
}

// rms_fuse2: v = p0+p1(f16)+bias+resid(bf16); out = rmsnorm -> f32
__global__ __launch_bounds__(256) void k_rms_fuse2(const u16* __restrict__ p0,
                                                   const u16* __restrict__ p1,
                                                   const float* __restrict__ bias,
                                                   const u16* __restrict__ residb,
                                                   const float* __restrict__ w,
                                                   float* __restrict__ of) {
  int row = blockIdx.x;
  int t = threadIdx.x;
  size_t base = (size_t)row * 2048 + t * 8;
  ushortx8 a = *(const ushortx8*)(p0 + base);
  ushortx8 b = *(const ushortx8*)(p1 + base);
  ushortx8 rb = *(const ushortx8*)(residb + base);
  float4 c0 = *(const float4*)(bias + t * 8);
  float4 c1 = *(const float4*)(bias + t * 8 + 4);
  float cc[8] = {c0.x, c0.y, c0.z, c0.w, c1.x, c1.y, c1.z, c1.w};
  float v[8];
#pragma unroll
  for (int e = 0; e < 8; ++e)
    v[e] = h2f((u16)a[e]) + h2f((u16)b[e]) + bf2f((u16)rb[e]) + cc[e];
  float ss = 0.f;
#pragma unroll
  for (int e = 0; e < 8; ++e) ss += v[e] * v[e];
#pragma unroll
  for (int d = 1; d < 64; d <<= 1) ss += __shfl_xor(ss, d);
  __shared__ float sred[4];
  if ((t & 63) == 0) sred[t >> 6] = ss;
  __syncthreads();
  float tot = sred[0] + sred[1] + sred[2] + sred[3];
  float scale = rsqrtf(tot * (1.0f / 2048.0f) + 1e-6f);
  const float* wp = w + t * 8;
  float4 f0, f1;
  f0.x = v[0] * wp[0] * scale; f0.y = v[1] * wp[1] * scale;
  f0.z = v[2] * wp[2] * scale; f0.w = v[3] * wp[3] * scale;
  f1.x = v[4] * wp[4] * scale; f1.y = v[5] * wp[5] * scale;
  f1.z = v[6] * wp[6] * scale; f1.w = v[7] * wp[7] * scale;
  *(float4*)(of + base) = f0;
  *(float4*)(of + base + 4) = f1;
}

// ---------------- launcher ----------------
extern "C" void kernel_launch(void* const* d_in, const int* in_sizes, int n_in,
                              void* d_out, int out_size, void* d_ws, size_t ws_size,
                              hipStream_t stream) {
  const float* x     = (const float*)d_in[0];
  const int*   amask = (const int*)d_in[1];
  const float* w_qkv = (const float*)d_in[2];
  const float* b_qkv = (const float*)d_in[3];
  const float* w_o   = (const float*)d_in[4];
  const float* b_o   = (const float*)d_in[5];
  const float* ln1_w = (const float*)d_in[6];
  const float* w1    = (const float*)d_in[7];
  const float* b1    = (const float*)d_in[8];
  const float* w2    = (const float*)d_in[9];
  const float* b2    = (const float*)d_in[10];
  const float* ln2_w = (const float*)d_in[11];
  float* out = (float*)d_out;

  char* ws = (char*)d_ws;
  u16*   xb    = (u16*)(ws + 0);              // 16,777,216
  u16*   wqkvT = (u16*)(ws + 16777216);       // 25,165,824
  u16*   woT   = (u16*)(ws + 41943040);       //  8,388,608
  u16*   w1Tp  = (u16*)(ws + 50331648);       // 67,108,864
  u16*   w2T   = (u16*)(ws + 117440512);      // 33,554,432
  float* ctab  = (float*)(ws + 150994944);    //    524,288
  float* stab  = (float*)(ws + 151519232);    //    524,288
  u16*   qr    = (u16*)(ws + 202375168);      // 16,777,216
  u16*   kr    = (u16*)(ws + 219152384);      // 16,777,216
  u16*   vt    = (u16*)(ws + 235929600);      // 16,777,216
  u16*   aout  = (u16*)(ws + 252706816);      // 16,777,216
  u16*   x1b   = (u16*)(ws + 303038464);      // 16,777,216
  // f16 partials (2 x 4096x2048 x 2B = 33.5 MB per pair), aliased over dead regions
  u16*   p01a  = (u16*)(ws + 152043520);      // 33,554,432 (alias)
  u16*   act   = (u16*)(ws + 152043520);      // 67,108,864 (alias, after rms_fuse1)
  u16*   p01b  = (u16*)(ws + 219152384);      // 33,554,432 (alias)

  // fused prep: cvt + 3 transposes + w1p + rope tables (one launch)
  k_prep<<<20992, 256, 0, stream>>>(x, xb, w_qkv, wqkvT, w_o, woT, w2, w2T,
                                    w1, w1Tp, ctab, stab);

  // G1 fused (128x256 tiles, 768 blocks = 3 perfect waves): qkv GEMM + bias
  // + rope -> qr/kr (q prescaled) ; v -> vt
  k_gemm128<<<768, 512, 0, stream>>>(xb, wqkvT, b_qkv, qr, kr, vt, ctab, stab);
  k_attn<<<256, 512, 0, stream>>>(qr, kr, vt, amask, aout);

  // G2 (split-K x2, f16 partials): x1 = rmsnorm(p0+p1+b_o+x, ln1_w)
  k_gemm256<2><<<16 * 8 * 2, 512, 0, stream>>>(aout, woT, p01a, nullptr,
                                               4096, 2048, 2048, 2);
  k_rms_fuse1<<<4096, 256, 0, stream>>>(p01a, p01a + (size_t)4096 * 2048, b_o, x, ln1_w, x1b);

  // G3 fused: act = (x1@w1_h + b1_h) * gelu(x1@w1_g + b1_g)   [4096][8192] bf16
  k_gemm256<3><<<16 * 64, 512, 0, stream>>>(x1b, w1Tp, act, b1,
                                            4096, 16384, 2048, 1);

  // G4 (split-K x2, f16 partials): out = rmsnorm(p0+p1+b2+x1b, ln2_w)
  k_gemm256<2><<<16 * 8 * 2, 512, 0, stream>>>(act, w2T, p01b, nullptr,
                                               4096, 2048, 8192, 2);
  k_rms_fuse2<<<4096, 256, 0, stream>>>(p01b, p01b + (size_t)4096 * 2048, b2, x1b, ln2_w, out);
}

// Round 20
// 810.518 us; speedup vs baseline: 1.0090x; 1.0090x over previous
//
#include <hip/hip_runtime.h>
#include <cstdint>
#include <cstring>

typedef unsigned short u16;
typedef __attribute__((ext_vector_type(8))) short short8;     // 8 bf16 for MFMA A/B
typedef __attribute__((ext_vector_type(8))) unsigned short ushortx8;
typedef __attribute__((ext_vector_type(4))) float floatx4;    // MFMA C/D

#define DEV __device__ __forceinline__

DEV u16 f2bf(float f) {
  union { float f; uint32_t u; } x; x.f = f;
  uint32_t r = x.u + 0x7fffu + ((x.u >> 16) & 1u);   // RNE
  return (u16)(r >> 16);
}
DEV float bf2f(u16 h) {
  union { float f; uint32_t u; } x; x.u = ((uint32_t)h) << 16;
  return x.f;
}
DEV u16 f2h(float f) {                                 // f32 -> f16 bits (v_cvt, RNE)
  union { u16 u; _Float16 h; } x; x.h = (_Float16)f; return x.u;
}
DEV float h2f(u16 h) {
  union { u16 u; _Float16 h; } x; x.u = h; return (float)x.h;
}
DEV float fexp2(float x) { return __builtin_amdgcn_exp2f(x); }  // v_exp_f32 (base-2)
// tanh-formulation gelu, branchless, hw v_exp_f32. |err| vs exact erf-gelu < 1e-3.
DEV float fast_gelu(float g) {
  float u = 0.7978845608f * (g + 0.044715f * g * g * g);
  float e = fexp2(-2.885390082f * fabsf(u));          // exp(-2u) = exp2(-2*log2e*u)
  float th = (1.0f - e) / (1.0f + e);
  th = (u < 0.0f) ? -th : th;
  return 0.5f * g * (1.0f + th);
}
// async global->LDS, 16B per lane. LDS dest = wave-uniform base + lane*16.
DEV void gload_lds16(const void* g, void* lds) {
  __builtin_amdgcn_global_load_lds(
      (const __attribute__((address_space(1))) char*)(uintptr_t)g,
      (__attribute__((address_space(3))) char*)(uintptr_t)lds, 16, 0, 0);
}

// ---------------- fused prep: cvt + 3 transposes + w1p + rope tables ----------------
// [0,4096) x->bf16 ; [4096,12288) wqkv/wo/w2 transpose ; [12288,20480) w1p ;
// [20480,20992) rope tables. Block-uniform branches.
__global__ __launch_bounds__(256) void k_prep(const float* __restrict__ x,
                                              u16* __restrict__ xb,
                                              const float* __restrict__ Wq,
                                              u16* __restrict__ WqT,
                                              const float* __restrict__ Wo,
                                              u16* __restrict__ WoT,
                                              const float* __restrict__ W2,
                                              u16* __restrict__ W2T,
                                              const float* __restrict__ W1,
                                              u16* __restrict__ W1Tp,
                                              float* __restrict__ ct,
                                              float* __restrict__ st) {
  __shared__ u16 t[64][70];
  const int id = blockIdx.x;
  if (id < 4096) {
    int i = (id * 256 + (int)threadIdx.x) * 8;
    float4 a = *(const float4*)(x + i);
    float4 b = *(const float4*)(x + i + 4);
    ushortx8 o;
    o[0] = f2bf(a.x); o[1] = f2bf(a.y); o[2] = f2bf(a.z); o[3] = f2bf(a.w);
    o[4] = f2bf(b.x); o[5] = f2bf(b.y); o[6] = f2bf(b.z); o[7] = f2bf(b.w);
    *(ushortx8*)(xb + i) = o;
  } else if (id < 20480) {
    const float* W; u16* Wt; int R, C, c0, r0;
    int src;                                     // source column (with w1 permute)
    int cx = threadIdx.x & 15, ry = threadIdx.x >> 4;
    if (id < 12288) {
      int tix;
      int i2 = id - 4096;
      if (i2 < 3072)      { W = Wq; Wt = WqT; R = 2048; C = 6144; tix = i2; }
      else if (i2 < 4096) { W = Wo; Wt = WoT; R = 2048; C = 2048; tix = i2 - 3072; }
      else                { W = W2; Wt = W2T; R = 8192; C = 2048; tix = i2 - 4096; }
      int ntc = C >> 6;
      c0 = (tix % ntc) * 64; r0 = (tix / ntc) * 64;
      src = c0 + cx * 4;
    } else {
      int iw = id - 12288;                       // 256 x 32 grid flattened
      W = W1; Wt = W1Tp; R = 2048; C = 16384;
      c0 = (iw & 255) * 64; r0 = (iw >> 8) * 64;
      int eta = c0 + cx * 4;
      int Bq = eta >> 8, ii = eta & 255, wn = (ii >> 6) & 3, rr = ii & 63,
          n = rr >> 4, tt = rr & 15;
      src = Bq * 128 + wn * 32 + (n & 1) * 16 + tt + ((n >= 2) ? 8192 : 0);
    }
#pragma unroll
    for (int i = 0; i < 4; ++i) {
      int row = ry + i * 16;
      float4 v = *(const float4*)(W + (size_t)(r0 + row) * C + src);
      ushort2 lo, hi;
      lo.x = f2bf(v.x); lo.y = f2bf(v.y);
      hi.x = f2bf(v.z); hi.y = f2bf(v.w);
      *(ushort2*)&t[row][cx * 4] = lo;
      *(ushort2*)&t[row][cx * 4 + 2] = hi;
    }
    __syncthreads();
#pragma unroll
    for (int i = 0; i < 4; ++i) {
      int col = ry + i * 16;
      ushort4 o;
      o.x = t[cx * 4 + 0][col]; o.y = t[cx * 4 + 1][col];
      o.z = t[cx * 4 + 2][col]; o.w = t[cx * 4 + 3][col];
      *(ushort4*)(Wt + (size_t)(c0 + col) * R + r0 + cx * 4) = o;
    }
  } else {
    int i = (id - 20480) * 256 + (int)threadIdx.x;  // < 2048*64
    int s = i >> 6, j = i & 63;
    float invf = 1.0f / powf(10000.0f, (float)j * (1.0f / 64.0f));
    float ang = (float)s * invf;
    ct[i] = cosf(ang);
    st[i] = sinf(ang);
  }
}

// ---------------- G1 GEMM 128x256 (8-wave, BK=32, quad-buffer, 768 blocks) -------
// qkv = x @ wqkvT^T + b; fused rope->qr/kr (q prescaled), v->vt transpose.
__global__ __launch_bounds__(512, 1) void k_gemm128(const u16* __restrict__ A,
                                                    const u16* __restrict__ Bt,
                                                    const float* __restrict__ bias,
                                                    u16* __restrict__ qrO,
                                                    u16* __restrict__ krO,
                                                    u16* __restrict__ vtO,
                                                    const float* __restrict__ ctabO,
                                                    const float* __restrict__ stabO) {
  constexpr int K = 2048;
  constexpr int nt = K / 32;                      // 64
  __shared__ __align__(16) u16 lds[4][12288];     // 96KB: per buf A[0,4096) B[4096,12288)
  const int tid = threadIdx.x;
  const int w = tid >> 6, lane = tid & 63;
  const int l15 = lane & 15, l4 = lane >> 4;
  const int wm = w >> 2, wn = w & 3;              // 2 x 4 waves; wave = 64x64 out
  const int xcd = blockIdx.x & 7, loc = blockIdx.x >> 3;
  const int swz = xcd * 96 + loc;
  const int bm = swz / 24, bn = swz % 24;

  const size_t abase = (size_t)bm * 128 * K;
  const size_t bbase = (size_t)bn * 256 * K;

  const int srA = tid >> 2;                       // A row (0..127)
  const int scA = (tid & 3) ^ ((srA >> 1) & 3);   // swizzled granule col
  auto stageA = [&](int kt) {
    gload_lds16(A + abase + (size_t)srA * K + kt * 32 + scA * 8,
                (void*)&lds[kt & 3][(size_t)tid * 8]);
  };
  auto stageB = [&](int kt, int li) {
    int g = li * 512 + tid;
    int row = g >> 2;
    int sc = (g & 3) ^ ((row >> 1) & 3);
    gload_lds16(Bt + bbase + (size_t)row * K + kt * 32 + sc * 8,
                (void*)&lds[kt & 3][4096 + (size_t)g * 8]);
  };
  const int fro = l15 * 32 + (l4 ^ ((l15 >> 1) & 3)) * 8;

  floatx4 acc[4][4];
  floatx4 zero = {0.f, 0.f, 0.f, 0.f};
#pragma unroll
  for (int m = 0; m < 4; ++m)
#pragma unroll
    for (int n = 0; n < 4; ++n) acc[m][n] = zero;

  for (int kt = 0; kt < 3; ++kt) { stageA(kt); stageB(kt, 0); stageB(kt, 1); }

  for (int t = 0; t < nt; ++t) {
    const int buf = t & 3;
    if (t < nt - 2)       asm volatile("s_waitcnt vmcnt(6)" ::: "memory");
    else if (t == nt - 2) asm volatile("s_waitcnt vmcnt(3)" ::: "memory");
    else                  asm volatile("s_waitcnt vmcnt(0)" ::: "memory");
    __builtin_amdgcn_sched_barrier(0);
    __builtin_amdgcn_s_barrier();
    const u16* Ab = &lds[buf][wm * 2048 + fro];
    const u16* Bb = &lds[buf][4096 + wn * 2048 + fro];
    short8 av[4], bv[4];
    // ---- phase 0: B all, A m0-1, 8 MFMA
#pragma unroll
    for (int n = 0; n < 4; ++n) bv[n] = *(const short8*)(Bb + n * 512);
    av[0] = *(const short8*)(Ab);
    av[1] = *(const short8*)(Ab + 512);
    if (t + 3 < nt) { stageA(t + 3); stageB(t + 3, 0); }
    asm volatile("s_waitcnt lgkmcnt(0)" ::: "memory");
    __builtin_amdgcn_sched_barrier(0);
    __builtin_amdgcn_s_setprio(1);
#pragma unroll
    for (int i = 0; i < 2; ++i)
#pragma unroll
      for (int n = 0; n < 4; ++n)
        acc[i][n] = __builtin_amdgcn_mfma_f32_16x16x32_bf16(av[i], bv[n], acc[i][n], 0, 0, 0);
    __builtin_amdgcn_s_setprio(0);
    __builtin_amdgcn_s_barrier();
    // ---- phase 1: A m2-3, 8 MFMA
    av[2] = *(const short8*)(Ab + 2 * 512);
    av[3] = *(const short8*)(Ab + 3 * 512);
    if (t + 3 < nt) stageB(t + 3, 1);
    asm volatile("s_waitcnt lgkmcnt(0)" ::: "memory");
    __builtin_amdgcn_sched_barrier(0);
    __builtin_amdgcn_s_setprio(1);
#pragma unroll
    for (int i = 0; i < 2; ++i)
#pragma unroll
      for (int n = 0; n < 4; ++n)
        acc[2 + i][n] = __builtin_amdgcn_mfma_f32_16x16x32_bf16(av[2 + i], bv[n], acc[2 + i][n], 0, 0, 0);
    __builtin_amdgcn_s_setprio(0);
  }

  // ---- fused epilogue: bounce full 128x256 tile through padded LDS [128][264]
  constexpr int PAD = 264;
  u16* T = (u16*)lds;                             // 128*264*2 = 67.6KB <= 96KB
  __syncthreads();                                // main-loop LDS reads complete
#pragma unroll
  for (int n = 0; n < 4; ++n) {
    float bb = bias[bn * 256 + wn * 64 + n * 16 + l15];
#pragma unroll
    for (int m = 0; m < 4; ++m)
#pragma unroll
      for (int j = 0; j < 4; ++j)
        T[(wm * 64 + m * 16 + l4 * 4 + j) * PAD + wn * 64 + n * 16 + l15] =
            f2bf(acc[m][n][j] + bb);
  }
  __syncthreads();
  const int bq = bm >> 4;                         // batch
  const int srow0 = (bm & 15) * 128;              // tile s base
  if (bn < 16) {
    // rope: task (sl 0..127, hh 0..1, t2 0..1) = tid
    int sl = tid >> 2, hh = (tid >> 1) & 1, t2 = tid & 1;
    const u16* row = T + sl * PAD + hh * 128;
    int s = srow0 + sl;
    int head = 2 * (bn & 7) + hh;
    u16* dst = (bn < 8 ? qrO : krO) +
               (((size_t)bq * 16 + head) * 2048 + s) * 128 + t2 * 64;
    const float* ctr = ctabO + (s << 6);
    const float* str2 = stabO + (s << 6);
    const float qs = (bn < 8) ? 0.12751744f : 1.0f;   // 1/sqrt(128)*log2(e) for q
#pragma unroll
    for (int ch = 0; ch < 8; ++ch) {
      int d0 = t2 * 64 + ch * 8;
      ushortx8 xv = *(const ushortx8*)(row + d0);
      float xp = bf2f(row[(d0 + 126) & 127]);     // x[d0-2] (wrap -> x[126])
      int f0 = d0 & 63;
      float4 c0v = *(const float4*)(ctr + f0);
      float4 c1v = *(const float4*)(ctr + f0 + 4);
      float4 s0v = *(const float4*)(str2 + f0);
      float4 s1v = *(const float4*)(str2 + f0 + 4);
      float cc[8] = {c0v.x, c0v.y, c0v.z, c0v.w, c1v.x, c1v.y, c1v.z, c1v.w};
      float sn[8] = {s0v.x, s0v.y, s0v.z, s0v.w, s1v.x, s1v.y, s1v.z, s1v.w};
      ushortx8 o;
#pragma unroll
      for (int pr = 0; pr < 4; ++pr) {
        float xe = bf2f((u16)xv[2 * pr]), xo = bf2f((u16)xv[2 * pr + 1]);
        o[2 * pr]     = f2bf((-xo * cc[2 * pr] + xp * sn[2 * pr]) * qs);
        o[2 * pr + 1] = f2bf(( xe * cc[2 * pr + 1] - xo * sn[2 * pr + 1]) * qs);
        xp = xe;
      }
      *(ushortx8*)(dst + ch * 8) = o;
    }
  } else {
    // v: in-reg 8x8 transpose -> vt[bq][head*128+d][s]
    int hh = tid >> 8, dg = (tid >> 4) & 15, sc2 = tid & 15;
    int head = 2 * (bn - 16) + hh;
    int s0 = srow0 + sc2 * 8;
    ushortx8 r[8];
#pragma unroll
    for (int i = 0; i < 8; ++i)
      r[i] = *(const ushortx8*)(T + (sc2 * 8 + i) * PAD + hh * 128 + dg * 8);
    u16* vbase = vtO + ((size_t)bq * 2048 + head * 128 + dg * 8) * 2048 + s0;
#pragma unroll
    for (int j2 = 0; j2 < 8; ++j2) {
      ushortx8 o;
#pragma unroll
      for (int i = 0; i < 8; ++i) o[i] = r[i][j2];
      *(ushortx8*)(vbase + (size_t)j2 * 2048) = o;
    }
  }
}

// ---------------- GEMM 256x256 deep-pipelined (8-wave, BK=32, quad-buffer) --------
// C[M][N] = A[M][K] @ Bt[N][K]^T, optional split-K (nsplit partials stacked in C).
// EPI 0: bf16 out = acc + bias. EPI 2: f16 raw partial (split-K).
// EPI 3: fused MLP front. Tile body: EXACT r3 structure.
template <int EPI>
__global__ __launch_bounds__(512, 2) void k_gemm256(const u16* __restrict__ A,
                                                    const u16* __restrict__ Bt,
                                                    void* __restrict__ C,
                                                    const float* __restrict__ bias,
                                                    int M, int N, int K, int nsplit) {
  __shared__ __align__(16) u16 lds[4][2][8192];   // 128 KiB: [buf][A/B][256*32]
  const int tid = threadIdx.x;
  const int w = tid >> 6, lane = tid & 63;
  const int l15 = lane & 15, l4 = lane >> 4;
  const int wm = w >> 2, wn = w & 3;              // wave grid 2 x 4
  const int nbn = N >> 8;
  const int nbm = M >> 8;

  int bm, bn, split = 0;
  if (nsplit == 1 && nbm == 16 && (nbn & 7) == 0) {
    const int xcd = blockIdx.x & 7, l = blockIdx.x >> 3;
    const int xr = xcd >> 1, xc = xcd & 1;
    const int stn = l >> 4, lbm = (l >> 2) & 3, lbn = l & 3;
    bm = xr * 4 + lbm;
    bn = xc * (nbn >> 1) + stn * 4 + lbn;
  } else {
    const int nwg = gridDim.x;
    const int q = nwg >> 3, r8 = nwg & 7;
    const int xcd = blockIdx.x & 7, loc = blockIdx.x >> 3;
    const int swz = (xcd < r8 ? xcd * (q + 1) : r8 * (q + 1) + (xcd - r8) * q) + loc;
    const int ntiles = nwg / nsplit;
    split = swz / ntiles;
    const int tix = swz % ntiles;
    bm = tix / nbn; bn = tix % nbn;
  }
  const int klen = K / nsplit;
  const int kofs = split * klen;

  const size_t abase = (size_t)bm * 256 * K + kofs;
  const size_t bbase = (size_t)bn * 256 * K + kofs;
  const int nt = klen >> 5;

  const int sr = tid >> 2;                        // row within half (0..127)
  const int sc = (tid & 3) ^ ((sr >> 1) & 3);     // swizzled granule col
  auto stage = [&](int kt, int li, int op) {
    const u16* src = op ? (Bt + bbase) : (A + abase);
    gload_lds16(src + (size_t)(li * 128 + sr) * K + kt * 32 + sc * 8,
                (void*)&lds[kt & 3][op][(li * 512 + w * 64) * 8]);
  };

  const int fro = l15 * 32 + (l4 ^ ((l15 >> 1) & 3)) * 8;

  floatx4 acc[8][4];
  floatx4 zero = {0.f, 0.f, 0.f, 0.f};
#pragma unroll
  for (int m = 0; m < 8; ++m)
#pragma unroll
    for (int n = 0; n < 4; ++n) acc[m][n] = zero;

  for (int kt = 0; kt < 3; ++kt)
    if (kt < nt) {
      stage(kt, 0, 0); stage(kt, 0, 1);
      stage(kt, 1, 0); stage(kt, 1, 1);
    }

  for (int t = 0; t < nt; ++t) {
    const int buf = t & 3;
    if (t < nt - 2)       asm volatile("s_waitcnt vmcnt(8)" ::: "memory");
    else if (t == nt - 2) asm volatile("s_waitcnt vmcnt(4)" ::: "memory");
    else                  asm volatile("s_waitcnt vmcnt(0)" ::: "memory");
    __builtin_amdgcn_sched_barrier(0);
    __builtin_amdgcn_s_barrier();            // all waves' tile-t loads landed
    const u16* Ab = &lds[buf][0][wm * 4096 + fro];
    const u16* Bb = &lds[buf][1][wn * 2048 + fro];
    short8 av[4], bv[4];
    // ---- phase 0: B all, A m0-3, 16 MFMA
#pragma unroll
    for (int n = 0; n < 4; ++n) bv[n] = *(const short8*)(Bb + n * 512);
#pragma unroll
    for (int i = 0; i < 4; ++i) av[i] = *(const short8*)(Ab + i * 512);
    if (t + 3 < nt) { stage(t + 3, 0, 0); stage(t + 3, 0, 1); }
    asm volatile("s_waitcnt lgkmcnt(0)" ::: "memory");
    __builtin_amdgcn_sched_barrier(0);
    __builtin_amdgcn_s_setprio(1);
#pragma unroll
    for (int i = 0; i < 4; ++i)
#pragma unroll
      for (int n = 0; n < 4; ++n)
        acc[i][n] = __builtin_amdgcn_mfma_f32_16x16x32_bf16(av[i], bv[n], acc[i][n], 0, 0, 0);
    __builtin_amdgcn_s_setprio(0);
    __builtin_amdgcn_s_barrier();
    // ---- phase 1: A m4-7, 16 MFMA (bv reused from regs)
#pragma unroll
    for (int i = 0; i < 4; ++i) av[i] = *(const short8*)(Ab + (4 + i) * 512);
    if (t + 3 < nt) { stage(t + 3, 1, 0); stage(t + 3, 1, 1); }
    asm volatile("s_waitcnt lgkmcnt(0)" ::: "memory");
    __builtin_amdgcn_sched_barrier(0);
    __builtin_amdgcn_s_setprio(1);
#pragma unroll
    for (int i = 0; i < 4; ++i)
#pragma unroll
      for (int n = 0; n < 4; ++n)
        acc[4 + i][n] = __builtin_amdgcn_mfma_f32_16x16x32_bf16(av[i], bv[n], acc[4 + i][n], 0, 0, 0);
    __builtin_amdgcn_s_setprio(0);
  }

  const int row0 = bm * 256 + wm * 128, col0 = bn * 256 + wn * 64;
  if (EPI == 2) {
    // f16 partials: |p| ~ O(1), f16 rel err 4.9e-4 -> negligible; halves traffic
    u16* P = (u16*)C + (size_t)split * M * N;
#pragma unroll
    for (int n = 0; n < 4; ++n) {
      int col = col0 + n * 16 + l15;
#pragma unroll
      for (int m = 0; m < 8; ++m)
#pragma unroll
        for (int j = 0; j < 4; ++j) {
          int row = row0 + m * 16 + l4 * 4 + j;
          P[(size_t)row * N + col] = f2h(acc[m][n][j]);
        }
    }
  } else if (EPI == 3) {
    // fused bias + act = a*gelu(g); pairing in-register via w1 permutation.
    __syncthreads();                              // main-loop LDS reads complete
    u16* ep = ((u16*)lds) + w * 4096;             // [128][32] u16 per wave
    const int colA = bn * 128 + wn * 32;          // act col base for this wave
#pragma unroll
    for (int n = 0; n < 2; ++n) {
      float ba = bias[colA + n * 16 + l15];
      float bg = bias[8192 + colA + n * 16 + l15];
#pragma unroll
      for (int m = 0; m < 8; ++m)
#pragma unroll
        for (int j = 0; j < 4; ++j) {
          float a = acc[m][n][j] + ba;
          float g = acc[m][n + 2][j] + bg;
          ep[(m * 16 + l4 * 4 + j) * 32 + n * 16 + l15] = f2bf(a * fast_gelu(g));
        }
    }
    const int rr = lane >> 2, cg = lane & 3;
    u16* Cg = (u16*)C;
    const int Nact = N >> 1;
#pragma unroll
    for (int pass = 0; pass < 8; ++pass) {
      short8 v = *(const short8*)&ep[(pass * 16 + rr) * 32 + cg * 8];
      size_t grow = row0 + pass * 16 + rr;
      *(short8*)&Cg[grow * Nact + colA + cg * 8] = v;
    }
  } else {
    // EPI 0: coalesced bf16 epilogue: per-wave 16KB LDS region, 128B row stores
    __syncthreads();                              // main-loop LDS reads complete
    u16* ep = ((u16*)lds) + w * 8192;             // [128][64] u16 per wave
#pragma unroll
    for (int n = 0; n < 4; ++n) {
      float bb = bias[col0 + n * 16 + l15];
#pragma unroll
      for (int m = 0; m < 8; ++m)
#pragma unroll
        for (int j = 0; j < 4; ++j)
          ep[(m * 16 + l4 * 4 + j) * 64 + n * 16 + l15] = f2bf(acc[m][n][j] + bb);
    }
    const int rr = lane >> 3, cg = lane & 7;
    u16* Cg = (u16*)C;
#pragma unroll
    for (int pass = 0; pass < 16; ++pass) {
      short8 v = *(const short8*)&ep[(pass * 8 + rr) * 64 + cg * 8];
      size_t grow = row0 + pass * 8 + rr;
      *(short8*)&Cg[grow * N + col0 + cg * 8] = v;
    }
  }
}

// ---------------- flash attention (QBLK=128, 8 waves, 512 blocks) ----------------
// Qr,Kr [B,H,S,HD] bf16 (q prescaled by scale*log2e) ; Vt [B,H,HD,S] ; O bf16
// r20: exact r18 configuration restored (best measured). QBLK=256 (r19)
// regressed: 1 block/CU lost the cross-block overlap that hides the
// staging-barrier serial sections. Softmax in exp2 units; T14 async-stage;
// branch-free state updates.
__global__ __launch_bounds__(512, 4) void k_attn(const u16* __restrict__ Qr,
                                                 const u16* __restrict__ Kr,
                                                 const u16* __restrict__ Vt,
                                                 const int* __restrict__ mask,
                                                 u16* __restrict__ O) {
  constexpr int S = 2048, HD = 128, H = 16;
  __shared__ __align__(16) u16 Ksh[64 * 128];   // [key][hd], swizzled
  __shared__ __align__(16) u16 Vsh[128 * 64];   // [hd][key], swizzled
  __shared__ __align__(16) u16 Psh[8][16 * 72]; // per-wave P, padded stride 72
  __shared__ float Msh[2048];

  const int bid = blockIdx.x;
  const int xcd = bid & 7, local = bid >> 3;    // 64 blocks per XCD
  const int bh = xcd * 4 + (local >> 4);        // 4 heads per XCD
  const int qt = local & 15;                    // 16 q-tiles of 128 rows
  const int b = bh >> 4, h = bh & 15;
  const int tid = threadIdx.x, wave = tid >> 6, lane = tid & 63;
  const int l15 = lane & 15, l4 = lane >> 4;
  const size_t bhs = (size_t)(b * H + h);
  const u16* Qb = Qr + bhs * S * HD;
  const u16* Kb = Kr + bhs * S * HD;
  const u16* Vb = Vt + bhs * HD * S;

  for (int i = tid; i < 2048; i += 512)
    Msh[i] = (mask[b * S + i] == 1) ? 0.0f : -1e30f;

  const int qrow = qt * 128 + wave * 16 + l15;
  short8 qf[4];
#pragma unroll
  for (int kk = 0; kk < 4; ++kk)
    qf[kk] = *(const short8*)&Qb[(size_t)qrow * HD + kk * 32 + l4 * 8];

  // staging geometry (same layout as the old gload_lds path)
  const int giA = tid, giB = 512 + tid;
  const int rKA = giA >> 4, gKA = giA & 15;
  const int rKB = giB >> 4, gKB = giB & 15;
  const int gsKA = (gKA & 8) | ((gKA ^ rKA) & 7);
  const int gsKB = (gKB & 8) | ((gKB ^ rKB) & 7);
  const int rVA = giA >> 3, gVA = giA & 7;
  const int rVB = giB >> 3, gVB = giB & 7;
  const int gsVA = (gVA ^ rVA) & 7;
  const int gsVB = (gVB ^ rVB) & 7;
  const u16* pKA = Kb + (size_t)rKA * HD + gsKA * 8;   // + ktile*8192
  const u16* pKB = Kb + (size_t)rKB * HD + gsKB * 8;
  const u16* pVA = Vb + (size_t)rVA * S + gsVA * 8;    // + ktile*64
  const u16* pVB = Vb + (size_t)rVB * S + gsVB * 8;

  float m_run[4], l_run[4];   // l_run: per-lane partial
  floatx4 o_acc[8];
  floatx4 zero = {0.f, 0.f, 0.f, 0.f};
#pragma unroll
  for (int j = 0; j < 4; ++j) { m_run[j] = -1e30f; l_run[j] = 0.f; }
#pragma unroll
  for (int n = 0; n < 8; ++n) o_acc[n] = zero;

  // prologue: load tile 0 into regs
  uint4 k0 = *(const uint4*)pKA;
  uint4 k1 = *(const uint4*)pKB;
  uint4 v0 = *(const uint4*)pVA;
  uint4 v1 = *(const uint4*)pVB;

  for (int ktile = 0; ktile < S / 64; ++ktile) {
    __builtin_amdgcn_sched_barrier(0);
    __builtin_amdgcn_s_barrier();       // all waves finished reading prev tile
    __builtin_amdgcn_sched_barrier(0);
    *(uint4*)&Ksh[(size_t)(0 * 512 + tid) * 8] = k0;
    *(uint4*)&Ksh[(size_t)(1 * 512 + tid) * 8] = k1;
    *(uint4*)&Vsh[(size_t)(0 * 512 + tid) * 8] = v0;
    *(uint4*)&Vsh[(size_t)(1 * 512 + tid) * 8] = v1;
    if (ktile + 1 < S / 64) {           // issue next tile's loads (stay in flight)
      k0 = *(const uint4*)(pKA + (size_t)(ktile + 1) * 8192);
      k1 = *(const uint4*)(pKB + (size_t)(ktile + 1) * 8192);
      v0 = *(const uint4*)(pVA + (size_t)(ktile + 1) * 64);
      v1 = *(const uint4*)(pVB + (size_t)(ktile + 1) * 64);
    }
    asm volatile("s_waitcnt lgkmcnt(0)" ::: "memory");  // own ds_writes done
    __builtin_amdgcn_sched_barrier(0);
    __builtin_amdgcn_s_barrier();       // all waves' writes visible
    __builtin_amdgcn_sched_barrier(0);

    floatx4 s_acc[4];
#pragma unroll
    for (int nf = 0; nf < 4; ++nf) s_acc[nf] = zero;
    __builtin_amdgcn_s_setprio(1);
#pragma unroll
    for (int kk = 0; kk < 4; ++kk) {
#pragma unroll
      for (int nf = 0; nf < 4; ++nf) {
        int key = nf * 16 + l15;
        int G = kk * 4 + l4;
        int lg = (G & 8) | ((G ^ key) & 7);
        short8 kv = *(const short8*)&Ksh[key * 128 + lg * 8];
        s_acc[nf] = __builtin_amdgcn_mfma_f32_16x16x32_bf16(qf[kk], kv, s_acc[nf], 0, 0, 0);
      }
    }
    __builtin_amdgcn_s_setprio(0);

    float p[4][4];
#pragma unroll
    for (int nf = 0; nf < 4; ++nf) {
      float ma = Msh[ktile * 64 + nf * 16 + l15];
#pragma unroll
      for (int j = 0; j < 4; ++j) p[nf][j] = s_acc[nf][j] + ma;   // exp2 units
    }
#pragma unroll
    for (int j = 0; j < 4; ++j) {
      float mx = fmaxf(fmaxf(p[0][j], p[1][j]), fmaxf(p[2][j], p[3][j]));
      mx = fmaxf(mx, __shfl_xor(mx, 1));
      mx = fmaxf(mx, __shfl_xor(mx, 2));
      mx = fmaxf(mx, __shfl_xor(mx, 4));
      mx = fmaxf(mx, __shfl_xor(mx, 8));
      float mnew = fmaxf(m_run[j], mx);
      float corr = fexp2(m_run[j] - mnew);
      float ps = 0.f;
#pragma unroll
      for (int nf = 0; nf < 4; ++nf) {
        p[nf][j] = fexp2(p[nf][j] - mnew);
        ps += p[nf][j];
      }
      l_run[j] = l_run[j] * corr + ps;
      m_run[j] = mnew;
#pragma unroll
      for (int n = 0; n < 8; ++n) o_acc[n][j] *= corr;
    }

#pragma unroll
    for (int nf = 0; nf < 4; ++nf)
#pragma unroll
      for (int j = 0; j < 4; ++j)
        Psh[wave][(l4 * 4 + j) * 72 + nf * 16 + l15] = f2bf(p[nf][j]);

    __builtin_amdgcn_s_setprio(1);
#pragma unroll
    for (int ks = 0; ks < 2; ++ks) {
      short8 pa = *(const short8*)&Psh[wave][l15 * 72 + ks * 32 + l4 * 8];
#pragma unroll
      for (int nf2 = 0; nf2 < 8; ++nf2) {
        int hd = nf2 * 16 + l15;
        int G = ks * 4 + l4;
        short8 vv = *(const short8*)&Vsh[hd * 64 + ((G ^ hd) & 7) * 8];
        o_acc[nf2] = __builtin_amdgcn_mfma_f32_16x16x32_bf16(pa, vv, o_acc[nf2], 0, 0, 0);
      }
    }
    __builtin_amdgcn_s_setprio(0);
  }

#pragma unroll
  for (int j = 0; j < 4; ++j) {
    float ls = l_run[j];
    ls += __shfl_xor(ls, 1); ls += __shfl_xor(ls, 2);
    ls += __shfl_xor(ls, 4); ls += __shfl_xor(ls, 8);
    l_run[j] = ls;
  }

#pragma unroll
  for (int j = 0; j < 4; ++j) {
    float inv = 1.0f / l_run[j];
    int srow = qt * 128 + wave * 16 + l4 * 4 + j;
    size_t orow = ((size_t)b * S + srow) * 2048 + h * 128;
#pragma unroll
    for (int nf2 = 0; nf2 < 8; ++nf2)
      O[orow + nf2 * 16 + l15] = f2bf(o_acc[nf2][j] * inv);
  }
}

// ---------------- fused split-K combine + rmsnorm over D=2048 ----------------
// rms_fuse1: v = p0+p1(f16)+bias+resid(f32); x1 = rmsnorm -> bf16 only
__global__ __launch_bounds__(256) void k_rms_fuse1(const u16* __restrict__ p0,
                                                   const u16* __restrict__ p1,
                                                   const float* __restrict__ bias,
                                                   const float* __restrict__ resid,
                                                   const float* __restrict__ w,
                                                   u16* __restrict__ ob) {
  int row = blockIdx.x;
  int t = threadIdx.x;
  size_t base = (size_t)row * 2048 + t * 8;
  ushortx8 a = *(const ushortx8*)(p0 + base);
  ushortx8 b = *(const ushortx8*)(p1 + base);
  float4 r0 = *(const float4*)(resid + base);
  float4 r1 = *(const float4*)(resid + base + 4);
  float4 c0 = *(const float4*)(bias + t * 8);
  float4 c1 = *(const float4*)(bias + t * 8 + 4);
  float rr[8] = {r0.x, r0.y, r0.z, r0.w, r1.x, r1.y, r1.z, r1.w};
  float cc[8] = {c0.x, c0.y, c0.z, c0.w, c1.x, c1.y, c1.z, c1.w};
  float v[8];
#pragma unroll
  for (int e = 0; e < 8; ++e)
    v[e] = h2f((u16)a[e]) + h2f((u16)b[e]) + rr[e] + cc[e];
  float ss = 0.f;
#pragma unroll
  for (int e = 0; e < 8; ++e) ss += v[e] * v[e];
#pragma unroll
  for (int d = 1; d < 64; d <<= 1) ss += __shfl_xor(ss, d);
  __shared__ float sred[4];
  if ((t & 63) == 0) sred[t >> 6] = ss;
  __syncthreads();
  float tot = sred[0] + sred[1] + sred[2] + sred[3];
  float scale = rsqrtf(tot * (1.0f / 2048.0f) + 1e-6f);
  const float* wp = w + t * 8;
  ushort4 q0, q1;
  q0.x = f2bf(v[0] * wp[0] * scale); q0.y = f2bf(v[1] * wp[1] * scale);
  q0.z = f2bf(v[2] * wp[2] * scale); q0.w = f2bf(v[3] * wp[3] * scale);
  q1.x = f2bf(v[4] * wp[4] * scale); q1.y = f2bf(v[5] * wp[5] * scale);
  q1.z = f2bf(v[6] * wp[6] * scale); q1.w = f2bf(v[7] * wp[7] * scale);
  *(ushort4*)(ob + base) = q0;
  *(ushort4*)(ob + base + 4) = q1;
}

// rms_fuse2: v = p0+p1(f16)+bias+resid(bf16); out = rmsnorm -> f32
__global__ __launch_bounds__(256) void k_rms_fuse2(const u16* __restrict__ p0,
                                                   const u16* __restrict__ p1,
                                                   const float* __restrict__ bias,
                                                   const u16* __restrict__ residb,
                                                   const float* __restrict__ w,
                                                   float* __restrict__ of) {
  int row = blockIdx.x;
  int t = threadIdx.x;
  size_t base = (size_t)row * 2048 + t * 8;
  ushortx8 a = *(const ushortx8*)(p0 + base);
  ushortx8 b = *(const ushortx8*)(p1 + base);
  ushortx8 rb = *(const ushortx8*)(residb + base);
  float4 c0 = *(const float4*)(bias + t * 8);
  float4 c1 = *(const float4*)(bias + t * 8 + 4);
  float cc[8] = {c0.x, c0.y, c0.z, c0.w, c1.x, c1.y, c1.z, c1.w};
  float v[8];
#pragma unroll
  for (int e = 0; e < 8; ++e)
    v[e] = h2f((u16)a[e]) + h2f((u16)b[e]) + bf2f((u16)rb[e]) + cc[e];
  float ss = 0.f;
#pragma unroll
  for (int e = 0; e < 8; ++e) ss += v[e] * v[e];
#pragma unroll
  for (int d = 1; d < 64; d <<= 1) ss += __shfl_xor(ss, d);
  __shared__ float sred[4];
  if ((t & 63) == 0) sred[t >> 6] = ss;
  __syncthreads();
  float tot = sred[0] + sred[1] + sred[2] + sred[3];
  float scale = rsqrtf(tot * (1.0f / 2048.0f) + 1e-6f);
  const float* wp = w + t * 8;
  float4 f0, f1;
  f0.x = v[0] * wp[0] * scale; f0.y = v[1] * wp[1] * scale;
  f0.z = v[2] * wp[2] * scale; f0.w = v[3] * wp[3] * scale;
  f1.x = v[4] * wp[4] * scale; f1.y = v[5] * wp[5] * scale;
  f1.z = v[6] * wp[6] * scale; f1.w = v[7] * wp[7] * scale;
  *(float4*)(of + base) = f0;
  *(float4*)(of + base + 4) = f1;
}

// ---------------- launcher ----------------
extern "C" void kernel_launch(void* const* d_in, const int* in_sizes, int n_in,
                              void* d_out, int out_size, void* d_ws, size_t ws_size,
                              hipStream_t stream) {
  const float* x     = (const float*)d_in[0];
  const int*   amask = (const int*)d_in[1];
  const float* w_qkv = (const float*)d_in[2];
  const float* b_qkv = (const float*)d_in[3];
  const float* w_o   = (const float*)d_in[4];
  const float* b_o   = (const float*)d_in[5];
  const float* ln1_w = (const float*)d_in[6];
  const float* w1    = (const float*)d_in[7];
  const float* b1    = (const float*)d_in[8];
  const float* w2    = (const float*)d_in[9];
  const float* b2    = (const float*)d_in[10];
  const float* ln2_w = (const float*)d_in[11];
  float* out = (float*)d_out;

  char* ws = (char*)d_ws;
  u16*   xb    = (u16*)(ws + 0);              // 16,777,216
  u16*   wqkvT = (u16*)(ws + 16777216);       // 25,165,824
  u16*   woT   = (u16*)(ws + 41943040);       //  8,388,608
  u16*   w1Tp  = (u16*)(ws + 50331648);       // 67,108,864
  u16*   w2T   = (u16*)(ws + 117440512);      // 33,554,432
  float* ctab  = (float*)(ws + 150994944);    //    524,288
  float* stab  = (float*)(ws + 151519232);    //    524,288
  u16*   qr    = (u16*)(ws + 202375168);      // 16,777,216
  u16*   kr    = (u16*)(ws + 219152384);      // 16,777,216
  u16*   vt    = (u16*)(ws + 235929600);      // 16,777,216
  u16*   aout  = (u16*)(ws + 252706816);      // 16,777,216
  u16*   x1b   = (u16*)(ws + 303038464);      // 16,777,216
  // f16 partials (2 x 4096x2048 x 2B = 33.5 MB per pair), aliased over dead regions
  u16*   p01a  = (u16*)(ws + 152043520);      // 33,554,432 (alias)
  u16*   act   = (u16*)(ws + 152043520);      // 67,108,864 (alias, after rms_fuse1)
  u16*   p01b  = (u16*)(ws + 219152384);      // 33,554,432 (alias)

  // fused prep: cvt + 3 transposes + w1p + rope tables (one launch)
  k_prep<<<20992, 256, 0, stream>>>(x, xb, w_qkv, wqkvT, w_o, woT, w2, w2T,
                                    w1, w1Tp, ctab, stab);

  // G1 fused (128x256 tiles, 768 blocks = 3 perfect waves): qkv GEMM + bias
  // + rope -> qr/kr (q prescaled) ; v -> vt
  k_gemm128<<<768, 512, 0, stream>>>(xb, wqkvT, b_qkv, qr, kr, vt, ctab, stab);
  k_attn<<<512, 512, 0, stream>>>(qr, kr, vt, amask, aout);

  // G2 (split-K x2, f16 partials): x1 = rmsnorm(p0+p1+b_o+x, ln1_w)
  k_gemm256<2><<<16 * 8 * 2, 512, 0, stream>>>(aout, woT, p01a, nullptr,
                                               4096, 2048, 2048, 2);
  k_rms_fuse1<<<4096, 256, 0, stream>>>(p01a, p01a + (size_t)4096 * 2048, b_o, x, ln1_w, x1b);

  // G3 fused: act = (x1@w1_h + b1_h) * gelu(x1@w1_g + b1_g)   [4096][8192] bf16
  k_gemm256<3><<<16 * 64, 512, 0, stream>>>(x1b, w1Tp, act, b1,
                                            4096, 16384, 2048, 1);

  // G4 (split-K x2, f16 partials): out = rmsnorm(p0+p1+b2+x1b, ln2_w)
  k_gemm256<2><<<16 * 8 * 2, 512, 0, stream>>>(act, w2T, p01b, nullptr,
                                               4096, 2048, 8192, 2);
  k_rms_fuse2<<<4096, 256, 0, stream>>>(p01b, p01b + (size_t)4096 * 2048, b2, x1b, ln2_w, out);
}